// Round 6
// baseline (167.939 us; speedup 1.0000x reference)
//
#include <hip/hip_runtime.h>
#include <math.h>

#define D2R      0.017453292519943295f
#define TWO_R    7917.6f                  /* 2 * 3958.8 miles */
#define RPI2     12435.698f               /* TWO_R * pi/2 */
#define TAU_LN2  0.17328679513998632f     /* tau * ln2 */
#define K_EXP2   5.770780163555854f       /* (1/tau) * log2(e) */
#define MBIG     1.0e30f
#define DMASK    2.0e30f
#define NBINS    125
#define P        8                        /* preds per group */
#define CH       1024                     /* candidates per chunk */
#define MAXCH    4                        /* M/CH = 4096/1024 */
#define NG_MAX   1152                     /* >= 8192/8 + 125 always */

__device__ __forceinline__ float fexp2(float x) { return __builtin_amdgcn_exp2f(x); }
__device__ __forceinline__ float rfl(float x) {
  return __int_as_float(__builtin_amdgcn_readfirstlane(__float_as_int(x)));
}

// ---- ws layout (bytes) ----
// 0     accF (f32) | 4 accI | 8 ngroups | 12 pad        <- memset 0..1040
// 16    hist[128]                                        <- memset
// 528   cursor[128]                                      <- memset
// 1040  pbase[128]
// 1552  wrec int4[NG_MAX]        {bin, pb|(pcount<<20), cnt, g}
// 19984 ptrig float4[8192]       {cosLat, sinLat, cosLon, sinLon} compacted
// 151056 pm float[NG_MAX*32]     partial min  [group][chunk][pred]
// 298512 ps float[NG_MAX*32]     partial sum
#define W_ACCF(w)   ((float*)(w))
#define W_ACCI(w)   ((int*)((char*)(w) + 4))
#define W_NG(w)     ((int*)((char*)(w) + 8))
#define W_HIST(w)   ((int*)((char*)(w) + 16))
#define W_CUR(w)    ((int*)((char*)(w) + 528))
#define W_PBASE(w)  ((int*)((char*)(w) + 1040))
#define W_WREC(w)   ((int4*)((char*)(w) + 1552))
#define W_PTRIG(w)  ((float4*)((char*)(w) + 19984))
#define W_PM(w)     ((float*)((char*)(w) + 151056))
#define W_PS(w)     ((float*)((char*)(w) + 298512))

// ---------- g1: per-bin histogram ----------
__global__ __launch_bounds__(256) void g1_hist(
    const int* __restrict__ xv, void* __restrict__ w, int B) {
  int i = blockIdx.x * 256 + threadIdx.x;
  if (i < B) {
    int bin = xv[3 * i] * 25 + xv[3 * i + 1] * 5 + xv[3 * i + 2];
    atomicAdd(&W_HIST(w)[bin], 1);
  }
}

// ---------- g2: scans (in LDS) + work-record build ----------
__global__ __launch_bounds__(128) void g2_scan(
    const int* __restrict__ bin_counts, void* __restrict__ w) {
  __shared__ int h[NBINS], cc[NBINS], pb[NBINS], gb[NBINS];
  const int t = threadIdx.x;
  if (t < NBINS) { h[t] = W_HIST(w)[t]; cc[t] = bin_counts[t]; }
  __syncthreads();
  if (t == 0) {
    int base = 0, g = 0;
    for (int b = 0; b < NBINS; ++b) {            // serial but LDS-only: ~1K cyc
      pb[b] = base; base += h[b];
      gb[b] = g;    g += (h[b] + P - 1) / P;
    }
    *W_NG(w) = g;
  }
  __syncthreads();
  if (t < NBINS) {
    W_PBASE(w)[t] = pb[t];
    int ng = (h[t] + P - 1) / P, g0 = gb[t], cnt = cc[t];
    for (int g = 0; g < ng; ++g) {
      int pbp = (pb[t] + g * P) | (min(P, h[t] - g * P) << 20);
      W_WREC(w)[g0 + g] = make_int4(t, pbp, cnt, g);
    }
  }
}

// ---------- g3: scatter preds into bin-compact order + trig ----------
__global__ __launch_bounds__(256) void g3_scatter(
    const float2* __restrict__ preds, const int* __restrict__ xv,
    void* __restrict__ w, int B) {
  int i = blockIdx.x * 256 + threadIdx.x;
  if (i < B) {
    int bin = xv[3 * i] * 25 + xv[3 * i + 1] * 5 + xv[3 * i + 2];
    int pos = W_PBASE(w)[bin] + atomicAdd(&W_CUR(w)[bin], 1);
    float2 p = preds[i];
    float sA, cA, sO, cO;
    __sincosf(p.y * D2R, &sA, &cA);
    __sincosf(p.x * D2R, &sO, &cO);
    W_PTRIG(w)[pos] = make_float4(cA, sA, cO, sO);
  }
}

// ---------- main: (group, chunk) -> partial (m, s) per pred ----------
// Uniform work: <=1024 candidates x 8 preds per block. Candidate trig is
// computed once per candidate and amortized over the 8 preds (whose trig
// sits in wave-uniform regs via readfirstlane).
__global__ __launch_bounds__(256) void lse_main(
    const float2* __restrict__ bc, void* __restrict__ w, int M) {
  const int gi = blockIdx.x >> 2;
  if (gi >= *W_NG(w)) return;
  const int c = blockIdx.x & 3;

  const int4 rec = W_WREC(w)[gi];
  const int bin = rec.x, cnt = rec.z;
  const int nch = (cnt + CH - 1) >> 10;
  if (c >= nch) return;
  const int pb = rec.y & 0xFFFFF;
  const int tid = threadIdx.x;

  const float4* __restrict__ ptrig = W_PTRIG(w);
  const int pcm1 = (rec.y >> 20) - 1;
  float cA[P], sA[P], cO[P], sO[P];
#pragma unroll
  for (int p = 0; p < P; ++p) {
    float4 t = ptrig[pb + min(p, pcm1)];
    cA[p] = rfl(t.x); sA[p] = rfl(t.y); cO[p] = rfl(t.z); sO[p] = rfl(t.w);
  }

  const float2* __restrict__ cb = bc + (size_t)bin * (size_t)M;
  const int c0 = c << 10;
  const int cend = min(cnt, c0 + CH);
  const int nst = (cend - c0 + 255) >> 8;      // 1..4 steps

  float m[P], s[P];
#pragma unroll
  for (int p = 0; p < P; ++p) { m[p] = MBIG; s[p] = 0.0f; }

  float2 cur = cb[min(c0 + tid, cend - 1)];
  for (int st = 0; st < nst; ++st) {
    const int idx = c0 + (st << 8) + tid;
    float2 nxt = cb[min(idx + 256, cend - 1)];  // 1-deep prefetch, in-bounds
    float sla, cla, slo, clo;
    __sincosf(cur.y * D2R, &sla, &cla);
    __sincosf(cur.x * D2R, &slo, &clo);
    const bool valid = idx < cend;
#pragma unroll
    for (int p = 0; p < P; ++p) {
      float pp    = cA[p] * cla;                    // cos1*cos2
      float cdlat = fmaf(sA[p], sla, pp);           // cos(dlat)
      float cdlon = fmaf(cO[p], clo, sO[p] * slo);  // cos(dlon)
      float t1 = fmaf(-0.5f, cdlat, 0.5f);
      float t2 = fmaf(-0.5f, cdlon, 0.5f);
      float a  = fminf(fmaxf(fmaf(pp, t2, t1), 0.0f), 1.0f);
      float x  = sqrtf(a);
      float pl = fmaf(x, -0.0012624911f, 0.0066700901f);   // A&S asin poly
      pl = fmaf(x, pl, -0.0170881256f);
      pl = fmaf(x, pl,  0.0308918810f);
      pl = fmaf(x, pl, -0.0501743046f);
      pl = fmaf(x, pl,  0.0889789874f);
      pl = fmaf(x, pl, -0.2145988016f);
      pl = fmaf(x, pl,  1.5707963050f);
      float wq = sqrtf(1.0f - x);
      float d  = fmaf(-TWO_R, wq * pl, RPI2);       // 2R*asin(sqrt(a))
      d = valid ? d : DMASK;
      float mn = fminf(m[p], d);
      s[p] = fmaf(s[p], fexp2((mn - m[p]) * K_EXP2), fexp2((mn - d) * K_EXP2));
      m[p] = mn;
    }
    cur = nxt;
  }

  // ---- wave reduce: min first, one rescale, then sum ----
#pragma unroll
  for (int p = 0; p < P; ++p) {
    float mw = m[p];
#pragma unroll
    for (int o = 32; o; o >>= 1) mw = fminf(mw, __shfl_xor(mw, o));
    float sp = s[p] * fexp2((mw - m[p]) * K_EXP2);
#pragma unroll
    for (int o = 32; o; o >>= 1) sp += __shfl_xor(sp, o);
    m[p] = mw; s[p] = sp;
  }

  // ---- cross-wave via LDS, then partial write ----
  __shared__ float redm[4][P], reds[4][P];
  const int wave = tid >> 6;
  if ((tid & 63) == 0) {
#pragma unroll
    for (int p = 0; p < P; ++p) { redm[wave][p] = m[p]; reds[wave][p] = s[p]; }
  }
  __syncthreads();
  if (tid < P) {
    float M4 = fminf(fminf(redm[0][tid], redm[1][tid]),
                     fminf(redm[2][tid], redm[3][tid]));
    float S4 = reds[0][tid] * fexp2((M4 - redm[0][tid]) * K_EXP2)
             + reds[1][tid] * fexp2((M4 - redm[1][tid]) * K_EXP2)
             + reds[2][tid] * fexp2((M4 - redm[2][tid]) * K_EXP2)
             + reds[3][tid] * fexp2((M4 - redm[3][tid]) * K_EXP2);
    W_PM(w)[gi * 32 + (c << 3) + tid] = M4;
    W_PS(w)[gi * 32 + (c << 3) + tid] = S4;
  }
}

// ---------- merge chunks per group, accumulate loss ----------
__global__ __launch_bounds__(64) void merge_kernel(void* __restrict__ w) {
  const int gi = blockIdx.x;
  if (gi >= *W_NG(w)) return;
  const int4 rec = W_WREC(w)[gi];
  const int cnt = rec.z;
  if (cnt <= 0) return;
  const int nch = (cnt + CH - 1) >> 10;
  const int pcount = rec.y >> 20;
  const int p = threadIdx.x;

  float soft = 0.0f;
  if (p < P) {
    float m = W_PM(w)[gi * 32 + p];
    float s = W_PS(w)[gi * 32 + p];
    for (int c = 1; c < nch; ++c) {
      float mo = W_PM(w)[gi * 32 + (c << 3) + p];
      float so = W_PS(w)[gi * 32 + (c << 3) + p];
      float mn = fminf(m, mo);
      s = fmaf(s, fexp2((mn - m) * K_EXP2), so * fexp2((mn - mo) * K_EXP2));
      m = mn;
    }
    float val = m - TAU_LN2 * __log2f(s);   // = -tau * logsumexp(-d/tau)
    soft = (p < pcount) ? val : 0.0f;
  }
#pragma unroll
  for (int o = 32; o; o >>= 1) soft += __shfl_xor(soft, o);
  if (p == 0) {
    atomicAdd(W_ACCF(w), soft);
    atomicAdd(W_ACCI(w), pcount);
  }
}

// ---------- finalize ----------
__global__ void fin_kernel(const void* __restrict__ w, float* __restrict__ out) {
  int nv = *W_ACCI((void*)w);
  if (nv < 1) nv = 1;
  out[0] = *W_ACCF((void*)w) / (float)nv;
}

extern "C" void kernel_launch(void* const* d_in, const int* in_sizes, int n_in,
                              void* d_out, int out_size, void* d_ws, size_t ws_size,
                              hipStream_t stream) {
  const float2* preds      = (const float2*)d_in[0];  // (B,2) [lon,lat] deg
  const float2* bin_coords = (const float2*)d_in[1];  // (125,M,2) [lon,lat] deg
  const int*    x_vals     = (const int*)d_in[2];     // (B,3)
  const int*    bin_counts = (const int*)d_in[3];     // (125,)
  float*        out        = (float*)d_out;

  const int B = in_sizes[0] / 2;
  const int M = (in_sizes[1] / 2) / NBINS;            // 4096

  hipMemsetAsync(d_ws, 0, 1040, stream);              // accF/accI/ngroups/hist/cursor

  const int pblk = (B + 255) / 256;
  g1_hist<<<pblk, 256, 0, stream>>>(x_vals, d_ws, B);
  g2_scan<<<1, 128, 0, stream>>>(bin_counts, d_ws);
  g3_scatter<<<pblk, 256, 0, stream>>>(preds, x_vals, d_ws, B);

  lse_main<<<NG_MAX * MAXCH, 256, 0, stream>>>(bin_coords, d_ws, M);

  merge_kernel<<<NG_MAX, 64, 0, stream>>>(d_ws);
  fin_kernel<<<1, 1, 0, stream>>>(d_ws, out);
}